// Round 3
// baseline (111.787 us; speedup 1.0000x reference)
//
#include <hip/hip_runtime.h>

// Multiprototypes: per-row squared distances to the 3 centers of the row's
// label, min-distance mean (loss1) and entropy-masked min-distance mean (loss2).
//
// B=262144, C=1000, K=3, D=64 (f32). HBM-bound: ~66 MB read -> ~10.4 us floor.
//
// Mapping: 16 lanes per row (one float4 each over D=64), 4 rows/wave,
// 4 waves/block, 2048 blocks -> 128 rows/block over 8 fully-unrolled
// iterations. Labels for all 8 iterations preloaded up front so the
// label->center dependent chain is broken; x/labels use non-temporal loads
// (streaming, keeps the 768 KB centers set hot in L2).

#define TH   0.95f
#define EPSF 1e-12f
#define NBLK 2048
#define BLK  256
#define ITERS 8   // rows_per_block(128) / rows_per_iter(16)

typedef float f4 __attribute__((ext_vector_type(4)));  // native vec for nt-load

__global__ __launch_bounds__(BLK) void mp_main(
    const float* __restrict__ x,        // [B, 64]
    const int*   __restrict__ labels,   // [B]
    const float* __restrict__ centers,  // [1000, 3, 64]
    float*       __restrict__ partials) // [3 * NBLK]
{
    const int tid  = threadIdx.x;
    const int lane = tid & 63;
    const int wave = tid >> 6;       // 0..3
    const int sub  = lane & 15;      // float4 slot within the row
    const int rsub = lane >> 4;      // row-within-wave 0..3

    const f4* __restrict__ x4 = (const f4*)x;
    const f4* __restrict__ c4 = (const f4*)centers;

    // each block-iter covers 16 consecutive rows
    const int rowbase = blockIdx.x * (16 * ITERS) + wave * 4 + rsub;

    // Preload all labels (independent loads; breaks the per-iter chain).
    int labs[ITERS];
    #pragma unroll
    for (int t = 0; t < ITERS; ++t)
        labs[t] = __builtin_nontemporal_load(&labels[rowbase + t * 16]);

    float s1 = 0.f, s2 = 0.f, sc = 0.f;

    #pragma unroll
    for (int t = 0; t < ITERS; ++t) {
        const int row = rowbase + t * 16;

        // coalesced: the wave reads 4 contiguous rows = 1024 B (streaming -> nt)
        const f4 xv = __builtin_nontemporal_load(&x4[row * 16 + sub]);

        const f4* cb = c4 + labs[t] * 48 + sub;  // lab*(K=3)*(16 float4/row)
        const f4 cv0 = cb[0];
        const f4 cv1 = cb[16];
        const f4 cv2 = cb[32];

        f4 d;
        d = xv - cv0;
        float a0 = d.x * d.x + d.y * d.y + d.z * d.z + d.w * d.w;
        d = xv - cv1;
        float a1 = d.x * d.x + d.y * d.y + d.z * d.z + d.w * d.w;
        d = xv - cv2;
        float a2 = d.x * d.x + d.y * d.y + d.z * d.z + d.w * d.w;

        // 16-lane butterfly: every lane of the group ends with full row sums
        #pragma unroll
        for (int m = 1; m <= 8; m <<= 1) {
            a0 += __shfl_xor(a0, m);
            a1 += __shfl_xor(a1, m);
            a2 += __shfl_xor(a2, m);
        }

        const float mn  = fminf(a0, fminf(a1, a2));
        const float mx  = fmaxf(a0, fmaxf(a1, a2));
        const float mid = a0 + a1 + a2 - mn - mx;   // second smallest

        const float d0 = mn + EPSF, d1 = mid + EPSF;
        const float p  = d0 / (d0 + d1);            // 0 < p <= 0.5
        const float q  = 1.f - p;
        const float ent = -(p * __log2f(p) + q * __log2f(q));
        const float msk = (ent <= TH) ? 1.f : 0.f;

        const float w = (sub == 0) ? 1.f : 0.f;     // count each row once
        s1 += w * mn;
        s2 += w * msk * mn;
        sc += w * msk;
    }

    // full-wave (64) butterfly reduce
    #pragma unroll
    for (int m = 1; m <= 32; m <<= 1) {
        s1 += __shfl_xor(s1, m);
        s2 += __shfl_xor(s2, m);
        sc += __shfl_xor(sc, m);
    }

    __shared__ float red[3][4];
    if (lane == 0) { red[0][wave] = s1; red[1][wave] = s2; red[2][wave] = sc; }
    __syncthreads();
    if (tid == 0) {
        partials[blockIdx.x]            = red[0][0] + red[0][1] + red[0][2] + red[0][3];
        partials[NBLK + blockIdx.x]     = red[1][0] + red[1][1] + red[1][2] + red[1][3];
        partials[2 * NBLK + blockIdx.x] = red[2][0] + red[2][1] + red[2][2] + red[2][3];
    }
}

__global__ __launch_bounds__(BLK) void mp_final(
    const float* __restrict__ partials, float* __restrict__ out, float invB)
{
    const int tid  = threadIdx.x;
    const int lane = tid & 63;
    const int wave = tid >> 6;

    float s1 = 0.f, s2 = 0.f, sc = 0.f;
    for (int i = tid; i < NBLK; i += BLK) {
        s1 += partials[i];
        s2 += partials[NBLK + i];
        sc += partials[2 * NBLK + i];
    }
    #pragma unroll
    for (int m = 1; m <= 32; m <<= 1) {
        s1 += __shfl_xor(s1, m);
        s2 += __shfl_xor(s2, m);
        sc += __shfl_xor(sc, m);
    }
    __shared__ float red[3][4];
    if (lane == 0) { red[0][wave] = s1; red[1][wave] = s2; red[2][wave] = sc; }
    __syncthreads();
    if (tid == 0) {
        float t1 = red[0][0] + red[0][1] + red[0][2] + red[0][3];
        float t2 = red[1][0] + red[1][1] + red[1][2] + red[1][3];
        float t3 = red[2][0] + red[2][1] + red[2][2] + red[2][3];
        out[0] = t1 * invB;    // loss1 = mean(min_pos)
        out[1] = t2 / t3;      // loss2 = masked mean
    }
}

extern "C" void kernel_launch(void* const* d_in, const int* in_sizes, int n_in,
                              void* d_out, int out_size, void* d_ws, size_t ws_size,
                              hipStream_t stream) {
    const float* x       = (const float*)d_in[0];
    const int*   labels  = (const int*)d_in[1];
    const float* centers = (const float*)d_in[2];
    float* out      = (float*)d_out;
    float* partials = (float*)d_ws;   // 3*NBLK floats = 24 KB
    const int B = in_sizes[1];        // 262144

    mp_main<<<NBLK, BLK, 0, stream>>>(x, labels, centers, partials);
    mp_final<<<1, BLK, 0, stream>>>(partials, out, 1.0f / (float)B);
}